// Round 2
// baseline (24.932 us; speedup 1.0000x reference)
//
#include <hip/hip_runtime.h>
#include <math.h>

// Output depends only on h2 at t=6 -> run 7 LSTM steps, 2 layers, fp32.
//
// R2 structure:
//  - 512 blocks x 320 threads, batch tile 8 (2 blocks/CU for latency hiding)
//  - thread = (batch-pair bp in [0,4), unit u in [0,20), gate-type q in [0,4))
//    with tid = bp*80 + u*4 + q  ->  the 4 gate types of (u, batch-pair) sit in
//    one lane-quad; update fused via DPP quad_perm broadcasts (no gate LDS).
//  - h1/h2 double-buffered in LDS -> 2 barriers/step (was 4), no gT round-trip.
//  - weights in registers (83/thread), c-state replicated across the quad.

constexpr int kT  = 7;
constexpr int kI  = 23;
constexpr int kH  = 20;
constexpr int kG  = 80;
constexpr int kBT = 8;     // batch tile
constexpr int kThreads = 320;

__device__ __forceinline__ float sigm(float v) {
    return __builtin_amdgcn_rcpf(1.0f + __builtin_amdgcn_exp2f(v * -1.44269504f));
}
__device__ __forceinline__ float tanh_(float v) {
    // 1 - 2/(exp2(v*2/ln2)+1): exact limits, no inf/inf
    return 1.0f - 2.0f * __builtin_amdgcn_rcpf(__builtin_amdgcn_exp2f(v * 2.88539008f) + 1.0f);
}
template<int J>
__device__ __forceinline__ float qb(float v) {
    // broadcast lane (quad_base+J)'s value to all 4 lanes of the quad
    return __int_as_float(__builtin_amdgcn_mov_dpp(__float_as_int(v), J * 0x55, 0xF, 0xF, true));
}
__device__ __forceinline__ void lstm_update(float a, float& c, float& h) {
    // a holds this lane's gate row value; quad lanes q=0..3 hold i,f,g,o
    const float gi = qb<0>(a);
    const float gf = qb<1>(a);
    const float gg = qb<2>(a);
    const float go = qb<3>(a);
    c = sigm(gf) * c + sigm(gi) * tanh_(gg);
    h = sigm(go) * tanh_(c);
}

__global__ __launch_bounds__(kThreads, 3) void lstm7_kernel(
    const float* __restrict__ x,
    const float* __restrict__ h0,
    const float* __restrict__ c0,
    const float* __restrict__ Wih0,
    const float* __restrict__ Whh0,
    const float* __restrict__ bih0,
    const float* __restrict__ bhh0,
    const float* __restrict__ Wih1,
    const float* __restrict__ Whh1,
    const float* __restrict__ bih1,
    const float* __restrict__ bhh1,
    const float* __restrict__ Wlin,
    const float* __restrict__ blin,
    float* __restrict__ out,
    int B)
{
    __shared__ __align__(16) float xS[kT][kI][kBT];    // [t][i][b]
    __shared__ __align__(16) float h1S[2][kH][kBT];    // double-buffered [buf][u][b]
    __shared__ __align__(16) float h2S[2][kH][kBT];

    const int tid = threadIdx.x;
    const int b0  = blockIdx.x * kBT;
    const int bp  = tid / kG;          // batch pair 0..3
    const int q   = tid & 3;           // gate type (i,f,g,o)
    const int u   = (tid % kG) >> 2;   // unit 0..19
    const int grow = q * kH + u;       // gate row in pytorch order
    const int bb  = bp * 2;            // batch offset in tile

    // ---- stage x[t=0..6] transposed ----
    for (int idx = tid; idx < kT * kI * kBT; idx += kThreads) {
        const int t = idx / (kI * kBT);
        const int r = idx % (kI * kBT);
        const int i = r / kBT;
        const int b = r % kBT;
        xS[t][i][b] = x[((size_t)t * B + b0 + b) * kI + i];
    }
    // ---- stage initial h (buffer 0) ----
    if (tid < kH * kBT) {
        const int uu = tid / kBT, b = tid % kBT;
        h1S[0][uu][b] = h0[(size_t)(b0 + b) * kH + uu];
        h2S[0][uu][b] = h0[(size_t)(B + b0 + b) * kH + uu];
    }

    // ---- weights -> registers ----
    float wA[kI], wB[kH], wC[kH], wD[kH];
    {
        const float* pa = Wih0 + grow * kI;
#pragma unroll
        for (int k = 0; k < kI; ++k) wA[k] = pa[k];
        const float4* pb = reinterpret_cast<const float4*>(Whh0 + grow * kH);
        const float4* pc = reinterpret_cast<const float4*>(Wih1 + grow * kH);
        const float4* pd = reinterpret_cast<const float4*>(Whh1 + grow * kH);
#pragma unroll
        for (int j = 0; j < 5; ++j) {
            const float4 vb = pb[j], vc = pc[j], vd = pd[j];
            wB[4*j] = vb.x; wB[4*j+1] = vb.y; wB[4*j+2] = vb.z; wB[4*j+3] = vb.w;
            wC[4*j] = vc.x; wC[4*j+1] = vc.y; wC[4*j+2] = vc.z; wC[4*j+3] = vc.w;
            wD[4*j] = vd.x; wD[4*j+1] = vd.y; wD[4*j+2] = vd.z; wD[4*j+3] = vd.w;
        }
    }
    const float bias1 = bih0[grow] + bhh0[grow];
    const float bias2 = bih1[grow] + bhh1[grow];

    // ---- c state, replicated across the quad (float2 = 2 batches) ----
    float2 c1, c2;
    c1.x = c0[(size_t)(b0 + bb) * kH + u];
    c1.y = c0[(size_t)(b0 + bb + 1) * kH + u];
    c2.x = c0[(size_t)(B + b0 + bb) * kH + u];
    c2.y = c0[(size_t)(B + b0 + bb + 1) * kH + u];

    __syncthreads();

#pragma unroll
    for (int t = 0; t < kT; ++t) {
        const int rb = t & 1, wb = rb ^ 1;

        // ========== layer 1 gates (read xS, h1S[rb]) ==========
        float a0 = bias1, a1 = bias1, e0 = 0.f, e1 = 0.f;
#pragma unroll
        for (int k = 0; k < kI; ++k) {
            const float2 v = *reinterpret_cast<const float2*>(&xS[t][k][bb]);
            if (k & 1) { e0 = fmaf(wA[k], v.x, e0); e1 = fmaf(wA[k], v.y, e1); }
            else       { a0 = fmaf(wA[k], v.x, a0); a1 = fmaf(wA[k], v.y, a1); }
        }
#pragma unroll
        for (int k = 0; k < kH; ++k) {
            const float2 v = *reinterpret_cast<const float2*>(&h1S[rb][k][bb]);
            if (k & 1) { e0 = fmaf(wB[k], v.x, e0); e1 = fmaf(wB[k], v.y, e1); }
            else       { a0 = fmaf(wB[k], v.x, a0); a1 = fmaf(wB[k], v.y, a1); }
        }
        a0 += e0; a1 += e1;

        // fused layer-1 update (quad gather via DPP), write h1S[wb]
        {
            float hx, hy;
            lstm_update(a0, c1.x, hx);
            lstm_update(a1, c1.y, hy);
            if (q == 0) *reinterpret_cast<float2*>(&h1S[wb][u][bb]) = make_float2(hx, hy);
        }
        __syncthreads();

        // ========== layer 2 gates (read h1S[wb] new, h2S[rb] old) ==========
        float g0 = bias2, g1 = bias2, f0 = 0.f, f1 = 0.f;
#pragma unroll
        for (int k = 0; k < kH; ++k) {
            const float2 v = *reinterpret_cast<const float2*>(&h1S[wb][k][bb]);
            if (k & 1) { f0 = fmaf(wC[k], v.x, f0); f1 = fmaf(wC[k], v.y, f1); }
            else       { g0 = fmaf(wC[k], v.x, g0); g1 = fmaf(wC[k], v.y, g1); }
        }
#pragma unroll
        for (int k = 0; k < kH; ++k) {
            const float2 v = *reinterpret_cast<const float2*>(&h2S[rb][k][bb]);
            if (k & 1) { f0 = fmaf(wD[k], v.x, f0); f1 = fmaf(wD[k], v.y, f1); }
            else       { g0 = fmaf(wD[k], v.x, g0); g1 = fmaf(wD[k], v.y, g1); }
        }
        g0 += f0; g1 += f1;

        // fused layer-2 update, write h2S[wb]
        {
            float hx, hy;
            lstm_update(g0, c2.x, hx);
            lstm_update(g1, c2.y, hy);
            if (q == 0) *reinterpret_cast<float2*>(&h2S[wb][u][bb]) = make_float2(hx, hy);
        }
        __syncthreads();
    }

    // ---- linear head on h2 of t=6 (in buffer (6&1)^1 = 1) ----
    if (tid < kBT) {
        const int b = tid;
        float acc = blin[0];
#pragma unroll
        for (int uu = 0; uu < kH; ++uu) {
            acc = fmaf(fmaxf(h2S[1][uu][b], 0.0f), Wlin[uu], acc);
        }
        out[b0 + b] = fmaxf(acc, 0.0f);
    }
}

extern "C" void kernel_launch(void* const* d_in, const int* in_sizes, int n_in,
                              void* d_out, int out_size, void* d_ws, size_t ws_size,
                              hipStream_t stream) {
    const float* x    = (const float*)d_in[0];
    const float* h0   = (const float*)d_in[1];
    const float* c0   = (const float*)d_in[2];
    const float* Wih0 = (const float*)d_in[3];
    const float* Whh0 = (const float*)d_in[4];
    const float* bih0 = (const float*)d_in[5];
    const float* bhh0 = (const float*)d_in[6];
    const float* Wih1 = (const float*)d_in[7];
    const float* Whh1 = (const float*)d_in[8];
    const float* bih1 = (const float*)d_in[9];
    const float* bhh1 = (const float*)d_in[10];
    const float* Wlin = (const float*)d_in[11];
    const float* blin = (const float*)d_in[12];
    float* out = (float*)d_out;

    const int B = in_sizes[1] / (2 * kH);  // h0 is [2, B, 20]
    const int blocks = B / kBT;            // 4096/8 = 512

    hipLaunchKernelGGL(lstm7_kernel, dim3(blocks), dim3(kThreads), 0, stream,
                       x, h0, c0, Wih0, Whh0, bih0, bhh0,
                       Wih1, Whh1, bih1, bhh1, Wlin, blin, out, B);
}